// Round 4
// baseline (720.938 us; speedup 1.0000x reference)
//
#include <hip/hip_runtime.h>

// NNMF fused: B=8192, NIN=3072, NOUT=512, 5 iterations.
// R4: producer/consumer wave specialization. Waves 0-3 (A) hold h MFMA-fragments
// in VGPRs for the whole iteration and produce r[s]; waves 4-7 (B) consume r[s-1]
// into tacc. W1/W2 rolling register prefetch (8-frag batches, 16-MFMA cover).
// x pre-transposed (X2T) to per-thread frag order: 1x 32B coalesced load/slot.
// L2 W-stream (~256KB/CU/slot) is the designed bottleneck (~223 us floor).

#define NIN 3072
#define NOUT 512

using bf16x8 = __attribute__((ext_vector_type(8))) short;
using f32x4  = __attribute__((ext_vector_type(4))) float;

__device__ __forceinline__ unsigned short f2bf(float f) {
    unsigned int u = __builtin_bit_cast(unsigned int, f);
    return (unsigned short)((u + 0x7fffu + ((u >> 16) & 1u)) >> 16);  // RNE
}
__device__ __forceinline__ float bf2f(unsigned short s) {
    unsigned int u = ((unsigned int)s) << 16;
    return __builtin_bit_cast(float, u);
}

// ---------------------------------------------------------------------------
// prep_w: shuffle W (fp32 [512][3072]) into MFMA-frag-native bf16 buffers.
// (verified in R2/R3 — unchanged)
// ---------------------------------------------------------------------------
__global__ void prep_w(const float* __restrict__ W,
                       unsigned short* __restrict__ W1,
                       unsigned short* __restrict__ W2) {
    int t = blockIdx.x * 256 + threadIdx.x;   // 0 .. 393215
    const int half = 196608;
    if (t < half) {
        int f = t >> 6, l = t & 63;
        int kcg = f >> 5, nt = f & 31;
        int n = nt * 16 + (l & 15);
        int k = kcg * 32 + ((l >> 4) << 3);
        unsigned short* dst = W2 + (size_t)t * 8;
        const float* src = W + (size_t)n * NIN + k;
        #pragma unroll
        for (int j = 0; j < 8; ++j) dst[j] = f2bf(src[j]);
    } else {
        int u = t - half;
        int f = u >> 6, l = u & 63;
        int ktg = f >> 4, nc = f & 15;
        int k = ktg * 16 + (l & 15);
        int nb = nc * 32 + ((l >> 4) << 3);
        unsigned short* dst = W1 + (size_t)u * 8;
        #pragma unroll
        for (int j = 0; j < 8; ++j) dst[j] = f2bf(W[(size_t)(nb + j) * NIN + k]);
    }
}

// ---------------------------------------------------------------------------
// prep_sum: invsum[b] = 1/(sum_k x[b][k] + eps). One wave per row.
// ---------------------------------------------------------------------------
__global__ void prep_sum(const float* __restrict__ x, float* __restrict__ invsum) {
    int row = blockIdx.x;
    int lane = threadIdx.x;  // 64
    const float4* r4 = reinterpret_cast<const float4*>(x + (size_t)row * NIN);
    float s = 0.f;
    #pragma unroll
    for (int c = 0; c < 12; ++c) {
        float4 v = r4[c * 64 + lane];
        s += v.x + v.y + v.z + v.w;
    }
    #pragma unroll
    for (int off = 32; off > 0; off >>= 1) s += __shfl_down(s, off, 64);
    if (lane == 0) invsum[row] = 1.0f / (s + 1e-20f);
}

// ---------------------------------------------------------------------------
// prep_xt: X2T[((blk*24+s)*256 + aw*64 + l)*16 + j] = bf16(x_norm[row][col])
//   j = m*8 + kt*4 + i;  row = blk*32 + m*16 + (l>>4)*4 + i;
//   col = s*128 + aw*32 + kt*16 + (l&15)
// So each main-kernel A-thread reads its 16 r-phase x values as one 32B chunk.
// ---------------------------------------------------------------------------
__global__ void prep_xt(const float* __restrict__ x, const float* __restrict__ invsum,
                        unsigned short* __restrict__ X2T) {
    int bb = blockIdx.x;            // 0..6143
    int blk = bb / 24, s = bb % 24;
    int t = threadIdx.x;            // 256
    int aw = t >> 6, l = t & 63, lo = l & 15, hi = l >> 4;
    unsigned short o[16];
    #pragma unroll
    for (int j = 0; j < 16; ++j) {
        int m = j >> 3, kt = (j >> 2) & 1, i = j & 3;
        int row = blk * 32 + m * 16 + hi * 4 + i;
        int col = s * 128 + aw * 32 + kt * 16 + lo;
        o[j] = f2bf(x[(size_t)row * NIN + col] * invsum[row]);
    }
    unsigned short* dst = X2T + (((size_t)blk * 24 + s) * 256 + t) * 16;
    *reinterpret_cast<uint4*>(dst)     = *reinterpret_cast<uint4*>(o);
    *reinterpret_cast<uint4*>(dst + 8) = *reinterpret_cast<uint4*>(o + 8);
}

// ---------------------------------------------------------------------------
// Main kernel. 256 blocks x 512 threads. Waves 0-3 = A (producer), 4-7 = B.
// Slot s: A computes denom[s] (h_frag regs x W1 regs), r[s] -> r_lds[s&1];
//         B consumes r[s-1] from r_lds[(s-1)&1] with W2[s-1] -> tacc.
// 25 slots/iter (A idle in 24, B idle in 0). Barrier counts match across paths.
// ---------------------------------------------------------------------------
__global__ __launch_bounds__(512, 2) void nnmf_main(
    const unsigned short* __restrict__ X2T,
    const unsigned short* __restrict__ W1,
    const unsigned short* __restrict__ W2,
    const float* __restrict__ h_init,
    float* __restrict__ out)
{
    __shared__ unsigned short h_lds[32 * 520];     // 33.3 KB, bf16 h operand cache
    __shared__ unsigned short r_lds[2][32 * 136];  // 17.4 KB double-buffered r
    __shared__ float red[4][32];

    const int tid = threadIdx.x;
    const int wv = tid >> 6, l = tid & 63, lo = l & 15, hi = l >> 4;
    const int b0 = blockIdx.x * 32;

    // init h_lds from h_initial (same value for every row)
    for (int idx = tid; idx < 32 * 512; idx += 512) {
        int r = idx >> 9, c = idx & 511;
        h_lds[r * 520 + c] = f2bf(h_init[c]);
    }

    if (wv < 4) {
        // ================= A path (producer) =================
        const int aw = wv;
        const unsigned short* w1b = W1 + (size_t)aw * 16384 + (size_t)l * 8; // +s*65536 +kt*8192 +nc*512
        const unsigned short* xb  = X2T + (((size_t)blockIdx.x * 24) * 256 + (size_t)(aw * 64 + l)) * 16;

        bf16x8 h_frag[2][16];
        bf16x8 w1p[8], w1q[8];

        // prime: w1p <- (s=0, nc 0..3)
        #pragma unroll
        for (int kt = 0; kt < 2; ++kt)
            #pragma unroll
            for (int n4 = 0; n4 < 4; ++n4)
                w1p[kt * 4 + n4] = *reinterpret_cast<const bf16x8*>(w1b + kt * 8192 + n4 * 512);

        for (int it = 0; it < 5; ++it) {
            __syncthreads();   // h_lds ready
            #pragma unroll
            for (int m = 0; m < 2; ++m)
                #pragma unroll
                for (int nc = 0; nc < 16; ++nc)
                    h_frag[m][nc] = *reinterpret_cast<const bf16x8*>(
                        &h_lds[(m * 16 + lo) * 520 + nc * 32 + hi * 8]);

            for (int s = 0; s < 25; ++s) {
                __syncthreads();
                if (s >= 24) continue;
                const int sn = (s + 1 == 24) ? 0 : s + 1;
                const unsigned short* w1s = w1b + (size_t)s * 65536;
                const unsigned short* w1n = w1b + (size_t)sn * 65536;

                // x for this slot (32B, consumed after the MFMAs)
                const unsigned short* xp = xb + (size_t)s * 4096;
                uint4 xa = *reinterpret_cast<const uint4*>(xp);
                uint4 xc = *reinterpret_cast<const uint4*>(xp + 8);

                f32x4 d[2][2];
                #pragma unroll
                for (int m = 0; m < 2; ++m) { d[m][0] = (f32x4){0,0,0,0}; d[m][1] = (f32x4){0,0,0,0}; }

                // batch1 loads (nc 4..7), MFMA batch0 (w1p = nc 0..3)
                #pragma unroll
                for (int kt = 0; kt < 2; ++kt)
                    #pragma unroll
                    for (int n4 = 0; n4 < 4; ++n4)
                        w1q[kt * 4 + n4] = *reinterpret_cast<const bf16x8*>(w1s + kt * 8192 + (4 + n4) * 512);
                #pragma unroll
                for (int n4 = 0; n4 < 4; ++n4) {
                    d[0][0] = __builtin_amdgcn_mfma_f32_16x16x32_bf16(h_frag[0][n4], w1p[n4],     d[0][0], 0,0,0);
                    d[1][0] = __builtin_amdgcn_mfma_f32_16x16x32_bf16(h_frag[1][n4], w1p[n4],     d[1][0], 0,0,0);
                    d[0][1] = __builtin_amdgcn_mfma_f32_16x16x32_bf16(h_frag[0][n4], w1p[4 + n4], d[0][1], 0,0,0);
                    d[1][1] = __builtin_amdgcn_mfma_f32_16x16x32_bf16(h_frag[1][n4], w1p[4 + n4], d[1][1], 0,0,0);
                }
                // batch2 loads (nc 8..11), MFMA batch1
                #pragma unroll
                for (int kt = 0; kt < 2; ++kt)
                    #pragma unroll
                    for (int n4 = 0; n4 < 4; ++n4)
                        w1p[kt * 4 + n4] = *reinterpret_cast<const bf16x8*>(w1s + kt * 8192 + (8 + n4) * 512);
                #pragma unroll
                for (int n4 = 0; n4 < 4; ++n4) {
                    d[0][0] = __builtin_amdgcn_mfma_f32_16x16x32_bf16(h_frag[0][4 + n4], w1q[n4],     d[0][0], 0,0,0);
                    d[1][0] = __builtin_amdgcn_mfma_f32_16x16x32_bf16(h_frag[1][4 + n4], w1q[n4],     d[1][0], 0,0,0);
                    d[0][1] = __builtin_amdgcn_mfma_f32_16x16x32_bf16(h_frag[0][4 + n4], w1q[4 + n4], d[0][1], 0,0,0);
                    d[1][1] = __builtin_amdgcn_mfma_f32_16x16x32_bf16(h_frag[1][4 + n4], w1q[4 + n4], d[1][1], 0,0,0);
                }
                // batch3 loads (nc 12..15), MFMA batch2
                #pragma unroll
                for (int kt = 0; kt < 2; ++kt)
                    #pragma unroll
                    for (int n4 = 0; n4 < 4; ++n4)
                        w1q[kt * 4 + n4] = *reinterpret_cast<const bf16x8*>(w1s + kt * 8192 + (12 + n4) * 512);
                #pragma unroll
                for (int n4 = 0; n4 < 4; ++n4) {
                    d[0][0] = __builtin_amdgcn_mfma_f32_16x16x32_bf16(h_frag[0][8 + n4], w1p[n4],     d[0][0], 0,0,0);
                    d[1][0] = __builtin_amdgcn_mfma_f32_16x16x32_bf16(h_frag[1][8 + n4], w1p[n4],     d[1][0], 0,0,0);
                    d[0][1] = __builtin_amdgcn_mfma_f32_16x16x32_bf16(h_frag[0][8 + n4], w1p[4 + n4], d[0][1], 0,0,0);
                    d[1][1] = __builtin_amdgcn_mfma_f32_16x16x32_bf16(h_frag[1][8 + n4], w1p[4 + n4], d[1][1], 0,0,0);
                }
                // next-slot batch0 loads, MFMA batch3
                #pragma unroll
                for (int kt = 0; kt < 2; ++kt)
                    #pragma unroll
                    for (int n4 = 0; n4 < 4; ++n4)
                        w1p[kt * 4 + n4] = *reinterpret_cast<const bf16x8*>(w1n + kt * 8192 + n4 * 512);
                #pragma unroll
                for (int n4 = 0; n4 < 4; ++n4) {
                    d[0][0] = __builtin_amdgcn_mfma_f32_16x16x32_bf16(h_frag[0][12 + n4], w1q[n4],     d[0][0], 0,0,0);
                    d[1][0] = __builtin_amdgcn_mfma_f32_16x16x32_bf16(h_frag[1][12 + n4], w1q[n4],     d[1][0], 0,0,0);
                    d[0][1] = __builtin_amdgcn_mfma_f32_16x16x32_bf16(h_frag[0][12 + n4], w1q[4 + n4], d[0][1], 0,0,0);
                    d[1][1] = __builtin_amdgcn_mfma_f32_16x16x32_bf16(h_frag[1][12 + n4], w1q[4 + n4], d[1][1], 0,0,0);
                }

                // r = x * rcp(denom + eps); write r_lds[s&1]
                union { uint4 v[2]; unsigned short u[16]; } xu;
                xu.v[0] = xa; xu.v[1] = xc;
                unsigned short* rb = r_lds[s & 1];
                #pragma unroll
                for (int m = 0; m < 2; ++m)
                    #pragma unroll
                    for (int kt = 0; kt < 2; ++kt)
                        #pragma unroll
                        for (int i = 0; i < 4; ++i) {
                            float xv = bf2f(xu.u[m * 8 + kt * 4 + i]);
                            float rv = xv * __builtin_amdgcn_rcpf(d[m][kt][i] + 1e-20f);
                            rb[(m * 16 + hi * 4 + i) * 136 + aw * 32 + kt * 16 + lo] = f2bf(rv);
                        }
            }
            __syncthreads();   // matches B's red barrier
            // (B updates h_lds after this barrier; A re-reads at next iteration top)
        }
    } else {
        // ================= B path (consumer) =================
        const int bw = wv - 4;
        const unsigned short* w2b = W2 + (size_t)bw * 4096 + (size_t)l * 8; // +s*65536 +kc*16384 +nt*512

        float h_reg[2][8][4];
        #pragma unroll
        for (int nt = 0; nt < 8; ++nt) {
            float hv = h_init[bw * 128 + nt * 16 + lo];
            #pragma unroll
            for (int m = 0; m < 2; ++m)
                #pragma unroll
                for (int i = 0; i < 4; ++i)
                    h_reg[m][nt][i] = hv;
        }

        f32x4 tacc[2][8];
        bf16x8 w2p[8], w2q[8];
        // prime: w2p <- (s=0, kc=0)
        #pragma unroll
        for (int nt = 0; nt < 8; ++nt)
            w2p[nt] = *reinterpret_cast<const bf16x8*>(w2b + nt * 512);

        for (int it = 0; it < 5; ++it) {
            __syncthreads();   // h_lds ready (A loads h_frag)
            #pragma unroll
            for (int m = 0; m < 2; ++m)
                #pragma unroll
                for (int nt = 0; nt < 8; ++nt)
                    tacc[m][nt] = (f32x4){0.f, 0.f, 0.f, 0.f};

            for (int s = 0; s < 25; ++s) {
                __syncthreads();
                if (s < 1) continue;
                const int u = s - 1;
                const int un = (u + 1 == 24) ? 0 : u + 1;
                const unsigned short* w2s = w2b + (size_t)u * 65536;
                const unsigned short* w2n = w2b + (size_t)un * 65536;
                const unsigned short* rb = r_lds[u & 1];

                // kc1 loads, MFMA kc0 (w2p)
                #pragma unroll
                for (int nt = 0; nt < 8; ++nt)
                    w2q[nt] = *reinterpret_cast<const bf16x8*>(w2s + 16384 + nt * 512);
                {
                    bf16x8 ra0 = *reinterpret_cast<const bf16x8*>(&rb[lo * 136 + hi * 8]);
                    bf16x8 ra1 = *reinterpret_cast<const bf16x8*>(&rb[(16 + lo) * 136 + hi * 8]);
                    #pragma unroll
                    for (int nt = 0; nt < 8; ++nt) {
                        tacc[0][nt] = __builtin_amdgcn_mfma_f32_16x16x32_bf16(ra0, w2p[nt], tacc[0][nt], 0,0,0);
                        tacc[1][nt] = __builtin_amdgcn_mfma_f32_16x16x32_bf16(ra1, w2p[nt], tacc[1][nt], 0,0,0);
                    }
                }
                // kc2 loads, MFMA kc1 (w2q)
                #pragma unroll
                for (int nt = 0; nt < 8; ++nt)
                    w2p[nt] = *reinterpret_cast<const bf16x8*>(w2s + 2 * 16384 + nt * 512);
                {
                    bf16x8 ra0 = *reinterpret_cast<const bf16x8*>(&rb[lo * 136 + 32 + hi * 8]);
                    bf16x8 ra1 = *reinterpret_cast<const bf16x8*>(&rb[(16 + lo) * 136 + 32 + hi * 8]);
                    #pragma unroll
                    for (int nt = 0; nt < 8; ++nt) {
                        tacc[0][nt] = __builtin_amdgcn_mfma_f32_16x16x32_bf16(ra0, w2q[nt], tacc[0][nt], 0,0,0);
                        tacc[1][nt] = __builtin_amdgcn_mfma_f32_16x16x32_bf16(ra1, w2q[nt], tacc[1][nt], 0,0,0);
                    }
                }
                // kc3 loads, MFMA kc2 (w2p)
                #pragma unroll
                for (int nt = 0; nt < 8; ++nt)
                    w2q[nt] = *reinterpret_cast<const bf16x8*>(w2s + 3 * 16384 + nt * 512);
                {
                    bf16x8 ra0 = *reinterpret_cast<const bf16x8*>(&rb[lo * 136 + 64 + hi * 8]);
                    bf16x8 ra1 = *reinterpret_cast<const bf16x8*>(&rb[(16 + lo) * 136 + 64 + hi * 8]);
                    #pragma unroll
                    for (int nt = 0; nt < 8; ++nt) {
                        tacc[0][nt] = __builtin_amdgcn_mfma_f32_16x16x32_bf16(ra0, w2p[nt], tacc[0][nt], 0,0,0);
                        tacc[1][nt] = __builtin_amdgcn_mfma_f32_16x16x32_bf16(ra1, w2p[nt], tacc[1][nt], 0,0,0);
                    }
                }
                // next-slot kc0 loads, MFMA kc3 (w2q)
                #pragma unroll
                for (int nt = 0; nt < 8; ++nt)
                    w2p[nt] = *reinterpret_cast<const bf16x8*>(w2n + nt * 512);
                {
                    bf16x8 ra0 = *reinterpret_cast<const bf16x8*>(&rb[lo * 136 + 96 + hi * 8]);
                    bf16x8 ra1 = *reinterpret_cast<const bf16x8*>(&rb[(16 + lo) * 136 + 96 + hi * 8]);
                    #pragma unroll
                    for (int nt = 0; nt < 8; ++nt) {
                        tacc[0][nt] = __builtin_amdgcn_mfma_f32_16x16x32_bf16(ra0, w2q[nt], tacc[0][nt], 0,0,0);
                        tacc[1][nt] = __builtin_amdgcn_mfma_f32_16x16x32_bf16(ra1, w2q[nt], tacc[1][nt], 0,0,0);
                    }
                }
            }

            // ---- boundary: h_new = normalize(h * (1 + t)), fp32 in regs
            float p[2][4];
            #pragma unroll
            for (int m = 0; m < 2; ++m)
                #pragma unroll
                for (int i = 0; i < 4; ++i) p[m][i] = 0.f;
            #pragma unroll
            for (int m = 0; m < 2; ++m)
                #pragma unroll
                for (int nt = 0; nt < 8; ++nt)
                    #pragma unroll
                    for (int i = 0; i < 4; ++i) {
                        float v = h_reg[m][nt][i] * (1.f + tacc[m][nt][i]);  // EPSILON_0 = 1
                        h_reg[m][nt][i] = v;
                        p[m][i] += v;
                    }
            #pragma unroll
            for (int mask = 1; mask < 16; mask <<= 1)
                #pragma unroll
                for (int m = 0; m < 2; ++m)
                    #pragma unroll
                    for (int i = 0; i < 4; ++i)
                        p[m][i] += __shfl_xor(p[m][i], mask, 64);
            if (lo == 0) {
                #pragma unroll
                for (int m = 0; m < 2; ++m)
                    #pragma unroll
                    for (int i = 0; i < 4; ++i)
                        red[bw][m * 16 + hi * 4 + i] = p[m][i];
            }
            __syncthreads();   // red visible (matches A's extra barrier)
            float inv[2][4];
            #pragma unroll
            for (int m = 0; m < 2; ++m)
                #pragma unroll
                for (int i = 0; i < 4; ++i) {
                    int row = m * 16 + hi * 4 + i;
                    float S = red[0][row] + red[1][row] + red[2][row] + red[3][row];
                    inv[m][i] = 1.f / (S + 1e-20f);
                }

            if (it < 4) {
                #pragma unroll
                for (int m = 0; m < 2; ++m)
                    #pragma unroll
                    for (int nt = 0; nt < 8; ++nt)
                        #pragma unroll
                        for (int i = 0; i < 4; ++i) {
                            int row = m * 16 + hi * 4 + i;
                            int col = bw * 128 + nt * 16 + lo;
                            float hv = h_reg[m][nt][i] * inv[m][i];
                            h_reg[m][nt][i] = hv;
                            h_lds[row * 520 + col] = f2bf(hv);
                        }
            } else {
                #pragma unroll
                for (int m = 0; m < 2; ++m)
                    #pragma unroll
                    for (int nt = 0; nt < 8; ++nt)
                        #pragma unroll
                        for (int i = 0; i < 4; ++i) {
                            int row = m * 16 + hi * 4 + i;
                            int col = bw * 128 + nt * 16 + lo;
                            out[(size_t)(b0 + row) * 512 + col] = h_reg[m][nt][i] * inv[m][i];
                        }
            }
        }
    }
}

extern "C" void kernel_launch(void* const* d_in, const int* in_sizes, int n_in,
                              void* d_out, int out_size, void* d_ws, size_t ws_size,
                              hipStream_t stream) {
    const float* x   = (const float*)d_in[0];   // [8192][3072]
    const float* wgt = (const float*)d_in[1];   // [512][3072]
    const float* h0  = (const float*)d_in[2];   // [512]
    float* out = (float*)d_out;

    // workspace: X2T bf16 50,331,648 B | W1 bf16 3,145,728 B | W2 bf16 3,145,728 B
    unsigned short* X2T = (unsigned short*)d_ws;
    unsigned short* W1  = (unsigned short*)((char*)d_ws + 50331648);
    unsigned short* W2  = (unsigned short*)((char*)d_ws + 53477376);
    // invsum scratch lives in the tail of d_out (overwritten by final h store,
    // which happens strictly after prep_xt consumed it)
    float* invsum = out + (size_t)out_size - 8192;

    prep_sum<<<8192, 64, 0, stream>>>(x, invsum);
    prep_w<<<1536, 256, 0, stream>>>(wgt, W1, W2);
    prep_xt<<<6144, 256, 0, stream>>>(x, invsum, X2T);
    nnmf_main<<<256, 512, 0, stream>>>(X2T, W1, W2, h0, out);
}